// Round 5
// baseline (2102.955 us; speedup 1.0000x reference)
//
#include <hip/hip_runtime.h>
#include <stdint.h>

typedef float f32x4 __attribute__((ext_vector_type(4)));

#define NB 32
#define CI 1024
#define CO 256
#define NPIX 49
#define WOC 441               // floats per (o,c)
#define WOSTR (CI*WOC)        // 451584 floats per o
#define XNSTR (CI*NPIX)       // 50176 floats per n

#define OBLK 32               // o's per block
#define CCH 32                // c's per block
#define THREADS 448           // 7 waves; wave == oh
#define WFL 16128             // w LDS floats per buffer: 21 (ko,oh)-rows * 32 o * 24

// w LDS layout: float[(ko*7+oh)*32 + o][24]; row float t = half*12 + ol*3 + kj,
//   holding w[o][c][oh][3*half+ol][ko*3+kj]  (ow=3 duplicated in both halves).
// x LDS layout: float[padded-pixel(9x9)][36]: 32 n + 4 pad; halo pixels stay 0.

template<int MODE>   // 0: partials->ws, 1: atomicAdd->out
__global__ __launch_bounds__(THREADS, 2)
void lc2d_main(const float* __restrict__ x, const float* __restrict__ w,
               float* __restrict__ dst)
{
    __shared__ __align__(16) float xs[2][81*36];   // 23,328 B
    __shared__ __align__(16) float wf[2][WFL];     // 129,024 B  (total 152,352 <= 160K)

    const int bid = blockIdx.x;
    const int oct = bid >> 5, cc = bid & 31;
    const int o0 = oct * OBLK;
    const int c0 = cc * CCH;

    const int tid  = threadIdx.x;
    const int wv   = tid >> 6;          // wave id == oh
    const int lane = tid & 63;
    const int owh  = (tid >> 5) & 1;    // ow half: 0-3 / 3-6
    const int oo   = (tid >> 2) & 7;
    const int ng   = tid & 3;           // n-quads ng, ng+4

    // ---- w staging: 36 width-4 global_load_lds per wave per c ----
    // Wave chunk = 2304 floats = 3 dz-groups x 768.  Instr (dz,k), k in [0,12):
    //   LDS float = wv*2304 + (dz*12+k)*64 + lane   (HW: base + lane*4B)
    //   slot S = k*64+lane in [0,768): o = S/24, t = S%24,
    //   t = half*12 + ol*3 + kj, ow = 3*half+ol
    //   src = (o0+o)*WOSTR + c*WOC + oh2*63 + ow*9 + ko*3 + kj  (r2=3*wv+dz)
    uint32_t offs[12];
#pragma unroll
    for (int k = 0; k < 12; ++k) {
        int S  = k*64 + lane;
        int o  = S / 24;
        int t  = S - o*24;
        int half = (t >= 12) ? 1 : 0;
        int tt = t - half*12;
        int ol = tt / 3;
        int kj = tt - ol*3;
        int ow = 3*half + ol;
        offs[k] = (uint32_t)(((size_t)o * WOSTR + ow*9 + kj) * 4u);
    }
    uint32_t ohko[3];
#pragma unroll
    for (int dz = 0; dz < 3; ++dz) {
        int r2 = 3*wv + dz;                       // 0..20, bijective over (ko,oh)
        int ko = r2 / 7, oh2 = r2 - ko*7;
        ohko[dz] = (uint32_t)((oh2*63 + ko*3) * 4);
    }
    const char* wbase = (const char*)w + ((size_t)o0 * WOSTR + (size_t)c0 * WOC) * 4;

#define STAGE_W(BUF, CREL) do {                                                   \
    const char* wb_ = wbase + (size_t)(CREL) * (WOC*4);                           \
    char* db_ = (char*)&wf[BUF][0] + wv * 9216;                                   \
    _Pragma("unroll") for (int dz = 0; dz < 3; ++dz)                              \
    _Pragma("unroll") for (int k = 0; k < 12; ++k)                                \
        __builtin_amdgcn_global_load_lds(                                         \
            (const __attribute__((address_space(1))) void*)(wb_ + ohko[dz]        \
                + offs[k]),                                                       \
            (__attribute__((address_space(3))) void*)(db_ + (dz*12+k)*256),       \
            4, 0, 0);                                                             \
    } while (0)

    // ---- x staging descriptors ----
    int xsrc[4], xdst[4];
#pragma unroll
    for (int i = 0; i < 4; ++i) {
        int e = tid + THREADS*i;
        if (e < NB*NPIX) {
            int n = e / NPIX, ihw = e - n*NPIX;
            int ih = ihw / 7, iw = ihw - ih*7;
            xsrc[i] = n*XNSTR + c0*NPIX + ihw;
            xdst[i] = ((ih+1)*9 + (iw+1))*36 + n;
        } else { xsrc[i] = -1; xdst[i] = 0; }
    }

    f32x4 acc[4][4][2];   // [j: o=oo+8j][ol][s2: n-quad ng+4*s2]
#pragma unroll
    for (int j = 0; j < 4; ++j)
#pragma unroll
        for (int ol = 0; ol < 4; ++ol)
#pragma unroll
            for (int s2 = 0; s2 < 2; ++s2) acc[j][ol][s2] = (f32x4)0.f;

    // zero x LDS once (halo pixels stay zero; staging only writes interior)
    for (int i = tid; i < 2*81*36; i += THREADS) ((float*)xs)[i] = 0.f;

    float xv[4];
#pragma unroll
    for (int i = 0; i < 4; ++i) if (xsrc[i] >= 0) xv[i] = x[xsrc[i]];
    STAGE_W(0, 0);
    __syncthreads();                    // zeros visible; w(c0) drained
#pragma unroll
    for (int i = 0; i < 4; ++i) if (xsrc[i] >= 0) ((float*)xs)[xdst[i]] = xv[i];
    __syncthreads();                    // x(c0) visible

    for (int t = 0; t < CCH; ++t) {
        const int cur = t & 1;
        const bool more = (t + 1 < CCH);
        if (more) {
            STAGE_W(cur ^ 1, t + 1);            // full compute window to land
#pragma unroll
            for (int i = 0; i < 4; ++i) if (xsrc[i] >= 0) xv[i] = x[xsrc[i] + (t+1)*NPIX];
        }

        // ---- compute: 3 ko phases, no internal barriers ----
#pragma unroll
        for (int ko = 0; ko < 3; ++ko) {
            const int ihp = wv + ko;                 // padded row 0..8
            const float* xb = &xs[cur][0];
            f32x4 xr[6][2];
#pragma unroll
            for (int d = 0; d < 6; ++d)
#pragma unroll
                for (int s2 = 0; s2 < 2; ++s2)
                    xr[d][s2] = *(const f32x4*)(xb + (ihp*9 + owh*3 + d)*36 + (ng + 4*s2)*4);
#pragma unroll
            for (int j = 0; j < 4; ++j) {
                const char* wrow = (const char*)&wf[cur][0]
                    + (((ko*7 + wv)*32 + oo + 8*j)*96 + owh*48);
                const f32x4 wq0 = *(const f32x4*)(wrow);
                const f32x4 wq1 = *(const f32x4*)(wrow + 16);
                const f32x4 wq2 = *(const f32x4*)(wrow + 32);
#pragma unroll
                for (int ol = 0; ol < 4; ++ol)
#pragma unroll
                    for (int kj = 0; kj < 3; ++kj) {
                        const int tt = ol*3 + kj;
                        const float wvv = (tt < 4) ? wq0[tt]
                                        : (tt < 8) ? wq1[tt-4] : wq2[tt-8];
#pragma unroll
                        for (int s2 = 0; s2 < 2; ++s2)
                            acc[j][ol][s2] += xr[ol + kj][s2] * wvv;
                    }
            }
        }

        if (more) {
#pragma unroll
            for (int i = 0; i < 4; ++i)
                if (xsrc[i] >= 0) ((float*)&xs[cur ^ 1][0])[xdst[i]] = xv[i];
        }
        __syncthreads();                // drains staging; next buffers ready
    }

    // ---- epilogue (ow=3 hi-half duplicate dropped via ol<owh skip) ----
#pragma unroll
    for (int j = 0; j < 4; ++j) {
        const int og = o0 + oo + 8*j;
#pragma unroll
        for (int ol = 0; ol < 4; ++ol) {
            if (ol < owh) continue;
            const int ow = owh*3 + ol;
#pragma unroll
            for (int s2 = 0; s2 < 2; ++s2) {
                if (MODE == 0) {
                    size_t idx = ((((size_t)cc*CO + og)*7 + wv)*7 + ow)*NB + 4*(ng + 4*s2);
                    *(f32x4*)(dst + idx) = acc[j][ol][s2];
                } else {
#pragma unroll
                    for (int m = 0; m < 4; ++m) {
                        int n = 4*(ng + 4*s2) + m;
                        atomicAdd(dst + ((size_t)n*CO + og)*NPIX + wv*7 + ow,
                                  acc[j][ol][s2][m]);
                    }
                }
            }
        }
    }
#undef STAGE_W
}

__global__ void lc2d_fin_ws(const float* __restrict__ wsb, const float* __restrict__ bias,
                            float* __restrict__ out)
{
    const int b = blockIdx.x;            // 1792 = 256 o * 7 oh
    const int o = b / 7, oh = b % 7;
    const int t = threadIdx.x;
    if (t >= 224) return;
    const int ow = t >> 5, n = t & 31;
    float s = 0.f;
#pragma unroll
    for (int cc = 0; cc < 32; ++cc)
        s += wsb[((((size_t)cc*CO + o)*7 + oh)*7 + ow)*NB + n];
    const float v = s + bias[o*NPIX + oh*7 + ow];
    out[((size_t)n*CO + o)*NPIX + oh*7 + ow] = (v >= 0.f) ? v : 0.1f*v;
}

__global__ void lc2d_zero(float* __restrict__ out)
{
    out[blockIdx.x*256 + threadIdx.x] = 0.f;       // grid exact: 401408
}

__global__ void lc2d_fin_at(float* __restrict__ out, const float* __restrict__ bias)
{
    const int i = blockIdx.x*256 + threadIdx.x;    // grid exact: 401408
    const int rem = i % (CO*NPIX);
    const float v = out[i] + bias[rem];
    out[i] = (v >= 0.f) ? v : 0.1f*v;
}

extern "C" void kernel_launch(void* const* d_in, const int* in_sizes, int n_in,
                              void* d_out, int out_size, void* d_ws, size_t ws_size,
                              hipStream_t stream)
{
    const float* x = (const float*)d_in[0];
    const float* w = (const float*)d_in[1];
    const float* b = (const float*)d_in[2];
    float* out = (float*)d_out;

    const size_t ws_need = (size_t)32 * CO * NPIX * NB * 4;   // 51.4 MB partials
    if (ws_size >= ws_need) {
        lc2d_main<0><<<256, THREADS, 0, stream>>>(x, w, (float*)d_ws);
        lc2d_fin_ws<<<1792, 256, 0, stream>>>((const float*)d_ws, b, out);
    } else {
        lc2d_zero<<<1568, 256, 0, stream>>>(out);
        lc2d_main<1><<<256, THREADS, 0, stream>>>(x, w, out);
        lc2d_fin_at<<<1568, 256, 0, stream>>>(out, b);
    }
}